// Round 2
// baseline (396.668 us; speedup 1.0000x reference)
//
#include <hip/hip_runtime.h>
#include <hip/hip_bf16.h>

#define B_   4
#define CIN  64
#define HID  256
#define COUT 64
#define T_   16
#define H_   64
#define W_   64
#define HW_  (H_*W_)       // 4096
#define THW  (T_*HW_)      // 65536
#define EPS  1e-5f

typedef unsigned short ushort_t;
typedef unsigned int   uint_t;
typedef short bf16x8 __attribute__((ext_vector_type(8)));
typedef float f32x4  __attribute__((ext_vector_type(4)));

// ---- stats in static device memory -------------------------------------------
#define SM3   4096
#define SIS3  5120
#define SSES  6144
#define SAL   7168
#define SBE   8192
__device__ float g_stats[10240];
// per-(bb, pos-block, channel) partial sums from k_expand epilogue (stats1)
__device__ float g_eps [4*1024*256];
__device__ float g_epss[4*1024*256];
// packed bf16 weights in MFMA fragment order: [0:16384) expand, [16384:32768) proj
__device__ ushort_t g_wpack[32768];

__device__ __forceinline__ float bf2f(ushort_t u) {
    return __uint_as_float(((uint_t)u) << 16);
}
__device__ __forceinline__ ushort_t f2bf(float f) {
    uint_t u = __float_as_uint(f);
    uint_t r = u + 0x7fffu + ((u >> 16) & 1u);   // round-to-nearest-even
    return (ushort_t)(r >> 16);
}
__device__ __forceinline__ void loadnorm8(const ushort_t* p, float a, float bb,
                                          float* v) {
    uint4 u = *(const uint4*)p;
    uint_t uu[4] = {u.x, u.y, u.z, u.w};
    #pragma unroll
    for (int j = 0; j < 4; ++j) {
        v[2*j]   = fmaxf(fmaf(__uint_as_float(uu[j] << 16),         a, bb), 0.f);
        v[2*j+1] = fmaxf(fmaf(__uint_as_float(uu[j] & 0xffff0000u), a, bb), 0.f);
    }
}
__device__ __forceinline__ void unpacknorm(uint4 k, float a, float bb, float* v) {
    uint_t uu[4] = {k.x, k.y, k.z, k.w};
    #pragma unroll
    for (int j = 0; j < 4; ++j) {
        v[2*j]   = fmaxf(fmaf(__uint_as_float(uu[j] << 16),         a, bb), 0.f);
        v[2*j+1] = fmaxf(fmaf(__uint_as_float(uu[j] & 0xffff0000u), a, bb), 0.f);
    }
}

// ---- pack w1 + wproj into bf16 fragment order --------------------------------
__global__ __launch_bounds__(256) void k_prep(const float* __restrict__ w1,
                                              const float* __restrict__ wproj) {
    int idx = blockIdx.x*256 + threadIdx.x;        // 0..16383
    {
        int j = idx & 7, lane = (idx>>3) & 63, ot = (idx>>9) & 3;
        int ks = (idx>>11) & 1, wv = idx >> 12;
        int ln = lane & 15, q = lane >> 4;
        int o = wv*64 + ot*16 + ln, k = ks*32 + q*8 + j;
        g_wpack[idx] = f2bf(w1[o*CIN + k]);
    }
    {
        int j = idx & 7, lane = (idx>>3) & 63, ot = (idx>>9) & 3, kg = idx >> 11;
        int ln = lane & 15, q = lane >> 4;
        int o = ot*16 + ln, k = kg*32 + q*8 + j;
        g_wpack[16384 + idx] = f2bf(wproj[o*HID + k]);
    }
}

// ============ expand 1x1 via MFMA + fused per-channel stats1 partials =========
__global__ __launch_bounds__(256) void k_expand(const float* __restrict__ x,
                                                ushort_t* __restrict__ h1, int b0) {
    union SMem {
        ushort_t Bs[64*72];          // B[k][n], stride 72, rotated cols (18.4 KB)
        float    red[2][256][16];    // per-channel per-16lane partials (32 KB)
    };
    __shared__ SMem sm;
    const int tid = threadIdx.x;
    const int bb  = blockIdx.y, gb = b0 + bb;
    const int pos0 = blockIdx.x * 64;
    const int lane = tid & 63, wv = tid >> 6;
    const int q = lane >> 4, ln = lane & 15;

    bf16x8 af[2][4];
    #pragma unroll
    for (int ks = 0; ks < 2; ++ks)
        #pragma unroll
        for (int ot = 0; ot < 4; ++ot)
            af[ks][ot] = *(const bf16x8*)&g_wpack[(((wv*2+ks)*4+ot)<<9) + lane*8];

    #pragma unroll
    for (int i = 0; i < 4; ++i) {
        int lin = i*1024 + tid*4;
        int k = lin >> 6, n0 = lin & 63;
        float4 v = *(const float4*)&x[(size_t)(gb*CIN + k) * THW + pos0 + n0];
        ushort_t* d = &sm.Bs[k*72 + ((n0 + 16*((k>>3)&3)) & 63)];
        d[0] = f2bf(v.x); d[1] = f2bf(v.y); d[2] = f2bf(v.z); d[3] = f2bf(v.w);
    }
    __syncthreads();

    f32x4 acc[4][4];
    #pragma unroll
    for (int i = 0; i < 4; ++i)
        #pragma unroll
        for (int j = 0; j < 4; ++j)
            acc[i][j] = (f32x4){0.f,0.f,0.f,0.f};

    #pragma unroll
    for (int ks = 0; ks < 2; ++ks) {
        bf16x8 bfr[4];
        #pragma unroll
        for (int nt = 0; nt < 4; ++nt) {
            union { short s[8]; bf16x8 v; } bu;
            #pragma unroll
            for (int j = 0; j < 8; ++j) {
                int k = ks*32 + q*8 + j;
                int nn = (nt*16 + ln + 16*((k>>3)&3)) & 63;
                bu.s[j] = (short)sm.Bs[k*72 + nn];
            }
            bfr[nt] = bu.v;
        }
        #pragma unroll
        for (int ot = 0; ot < 4; ++ot)
            #pragma unroll
            for (int nt = 0; nt < 4; ++nt)
                acc[ot][nt] = __builtin_amdgcn_mfma_f32_16x16x32_bf16(
                    af[ks][ot], bfr[nt], acc[ot][nt], 0, 0, 0);
    }

    // epilogue: store + accumulate per-lane per-channel partial sums
    float sp_[16], ssp_[16];
    #pragma unroll
    for (int i = 0; i < 16; ++i) { sp_[i] = 0.f; ssp_[i] = 0.f; }

    #pragma unroll
    for (int ot = 0; ot < 4; ++ot)
        #pragma unroll
        for (int nt = 0; nt < 4; ++nt)
            #pragma unroll
            for (int r = 0; r < 4; ++r) {
                float vv = acc[ot][nt][r];
                int o = wv*64 + ot*16 + q*4 + r;
                int n = nt*16 + ln;
                h1[((size_t)bb*HID + o)*THW + pos0 + n] = f2bf(vv);
                sp_[ot*4+r] += vv;
                ssp_[ot*4+r] = fmaf(vv, vv, ssp_[ot*4+r]);
            }

    __syncthreads();           // all waves done reading Bs before union reuse
    #pragma unroll
    for (int i = 0; i < 16; ++i) {
        int o = wv*64 + (i>>2)*16 + q*4 + (i&3);
        sm.red[0][o][ln] = sp_[i];
        sm.red[1][o][ln] = ssp_[i];
    }
    __syncthreads();
    {
        float s = 0.f, ss = 0.f;
        #pragma unroll
        for (int l = 0; l < 16; ++l) {
            s  += sm.red[0][tid][l];
            ss += sm.red[1][tid][l];
        }
        size_t base = ((size_t)bb*1024 + blockIdx.x)*256 + tid;
        g_eps [base] = s;
        g_epss[base] = ss;
    }
}

// ===== fused stage2+stage3: spatial dw3x3 -> IN -> relu -> temporal dw3 =======
// one block (512 thr) per (bb, channel); dws output lives in keep[16] registers
__global__ __launch_bounds__(512) void k_mid(const ushort_t* __restrict__ h1,
                                             const float* __restrict__ wdws,
                                             const float* __restrict__ wdwt,
                                             ushort_t* __restrict__ h3) {
    const int tid = threadIdx.x;
    const int bc  = blockIdx.x;
    const int o   = bc & (HID-1);
    const int bb  = bc >> 8;
    const int wid = tid >> 6, lane = tid & 63;

    if (o >= 32 && o < 64) {                      // zero-forced TIM channels
        if (tid == 0) {
            g_stats[SM3  + bc] = 0.f;
            g_stats[SIS3 + bc] = 1.f / sqrtf(EPS);
            g_stats[SSES + bc] = 0.f;
        }
        return;
    }

    __shared__ float pl[2][64*66];                // double-buffered norm'd plane
    __shared__ float ls[8], lss[8];
    __shared__ float sa, sb;

    // ---- stats1 for this channel from k_expand partials (L3-hot, 8 KB) ------
    {
        const float* ps  = &g_eps [((size_t)bb*1024)*256 + o];
        const float* pss = &g_epss[((size_t)bb*1024)*256 + o];
        float s  = ps [(size_t)tid*256] + ps [((size_t)tid+512)*256];
        float ss = pss[(size_t)tid*256] + pss[((size_t)tid+512)*256];
        #pragma unroll
        for (int m = 32; m > 0; m >>= 1) {
            s  += __shfl_xor(s,  m);
            ss += __shfl_xor(ss, m);
        }
        if (lane == 0) { ls[wid] = s; lss[wid] = ss; }
        __syncthreads();
        if (tid == 0) {
            float st = 0.f, sst = 0.f;
            #pragma unroll
            for (int i = 0; i < 8; ++i) { st += ls[i]; sst += lss[i]; }
            float m = st * (1.f/THW);
            float v = sst * (1.f/THW) - m*m;
            float is = 1.f / sqrtf(v + EPS);
            sa = is; sb = -m * is;
        }
        __syncthreads();
    }
    const float a1 = sa, b1 = sb;

    const int fut = (o < 32) ? 1 : 0;             // TIM future-shifted channel
    const int y   = tid >> 3;
    const int x0  = (tid & 7) * 8;
    const ushort_t* chp = h1 + (size_t)bc * THW;

    float wf[9];
    #pragma unroll
    for (int k = 0; k < 9; ++k) wf[k] = wdws[o*9 + k];

    // prologue: stage normalized input plane for output t=0
    {
        const ushort_t* sp = chp + (size_t)(fut ? 1 : 0) * HW_ + tid*8;
        float v[8];
        loadnorm8(sp, a1, b1, v);
        float* dst = &pl[0][y*66 + x0];
        #pragma unroll
        for (int i = 0; i < 8; ++i) dst[i] = v[i];
    }
    __syncthreads();

    // ---- phase A: spatial 3x3 conv, outputs kept in registers ----------------
    uint4 keep[16];
    float s2 = 0.f, ss2 = 0.f;
    const int lastp = fut ? (T_-2) : (T_-1);      // last output with real input

    for (int t = 0; t < T_; ++t) {
        if (t < lastp) {                          // stage next plane, other buf
            int np = t + 1;
            const ushort_t* sp = chp + (size_t)(fut ? np+1 : np)*HW_ + tid*8;
            float v[8];
            loadnorm8(sp, a1, b1, v);
            float* dst = &pl[np & 1][y*66 + x0];
            #pragma unroll
            for (int i = 0; i < 8; ++i) dst[i] = v[i];
        }
        if (fut && t == T_-1) {
            keep[t] = (uint4){0u, 0u, 0u, 0u};    // TIM zero plane: dws out = 0
        } else {
            const float* plane = pl[t & 1];
            float v[3][10];
            #pragma unroll
            for (int dy = 0; dy < 3; ++dy) {
                int yy = y + dy - 1;
                if (yy < 0 || yy >= H_) {
                    #pragma unroll
                    for (int j = 0; j < 10; ++j) v[dy][j] = 0.f;
                } else {
                    const float* rp = &plane[yy*66];
                    v[dy][0] = (x0 == 0)  ? 0.f : rp[x0-1];
                    #pragma unroll
                    for (int i = 0; i < 8; ++i) v[dy][1+i] = rp[x0+i];
                    v[dy][9] = (x0 == 56) ? 0.f : rp[x0+8];
                }
            }
            uint_t outp[4];
            #pragma unroll
            for (int i2 = 0; i2 < 4; ++i2) {
                float o0 = 0.f, o1 = 0.f;
                #pragma unroll
                for (int dy = 0; dy < 3; ++dy)
                    #pragma unroll
                    for (int dx = 0; dx < 3; ++dx) {
                        float w = wf[dy*3+dx];
                        o0 = fmaf(w, v[dy][2*i2 + dx],     o0);
                        o1 = fmaf(w, v[dy][2*i2 + 1 + dx], o1);
                    }
                ushort_t u0 = f2bf(o0), u1 = f2bf(o1);
                float r0 = bf2f(u0), r1 = bf2f(u1);
                s2 += r0 + r1; ss2 = fmaf(r0, r0, fmaf(r1, r1, ss2));
                outp[i2] = (uint_t)u0 | ((uint_t)u1 << 16);
            }
            keep[t].x = outp[0]; keep[t].y = outp[1];
            keep[t].z = outp[2]; keep[t].w = outp[3];
        }
        __syncthreads();
    }

    // ---- phase B: stats2 block-reduce (never touches HBM) --------------------
    {
        float s = s2, ss = ss2;
        #pragma unroll
        for (int m = 32; m > 0; m >>= 1) {
            s  += __shfl_xor(s,  m);
            ss += __shfl_xor(ss, m);
        }
        if (lane == 0) { ls[wid] = s; lss[wid] = ss; }
        __syncthreads();
        if (tid == 0) {
            float st = 0.f, sst = 0.f;
            #pragma unroll
            for (int i = 0; i < 8; ++i) { st += ls[i]; sst += lss[i]; }
            float m = st * (1.f/THW);
            float v = sst * (1.f/THW) - m*m;
            float is = 1.f / sqrtf(v + EPS);
            sa = is; sb = -m * is;
        }
        __syncthreads();
    }
    const float a2 = sa, b2 = sb;
    // note: for fut channels keep[15]==0 -> unpacknorm gives relu(b2) == znorm

    // ---- phase C: temporal dw3 from registers, write h3, stats3 --------------
    const float w0 = wdwt[o*3+0], w1 = wdwt[o*3+1], w2 = wdwt[o*3+2];
    ushort_t* op = h3 + (size_t)bc * THW + tid*8;

    float p[8], c[8], n[8];
    #pragma unroll
    for (int i = 0; i < 8; ++i) p[i] = 0.f;
    unpacknorm(keep[0], a2, b2, c);
    unpacknorm(keep[1], a2, b2, n);

    float s3 = 0.f, ss3 = 0.f;
    #pragma unroll
    for (int t = 0; t < T_; ++t) {
        uint_t outp[4];
        #pragma unroll
        for (int i2 = 0; i2 < 4; ++i2) {
            float o0 = fmaf(w0, p[2*i2],   fmaf(w1, c[2*i2],   w2 * n[2*i2]));
            float o1 = fmaf(w0, p[2*i2+1], fmaf(w1, c[2*i2+1], w2 * n[2*i2+1]));
            ushort_t u0 = f2bf(o0), u1 = f2bf(o1);
            float r0 = bf2f(u0), r1 = bf2f(u1);
            s3 += r0 + r1; ss3 = fmaf(r0, r0, fmaf(r1, r1, ss3));
            outp[i2] = (uint_t)u0 | ((uint_t)u1 << 16);
        }
        uint4 r; r.x = outp[0]; r.y = outp[1]; r.z = outp[2]; r.w = outp[3];
        *(uint4*)(op + (size_t)t*HW_) = r;

        #pragma unroll
        for (int i = 0; i < 8; ++i) { p[i] = c[i]; c[i] = n[i]; }
        if (t + 2 < T_) unpacknorm(keep[t+2], a2, b2, n);
        else {
            #pragma unroll
            for (int i = 0; i < 8; ++i) n[i] = 0.f;   // true conv zero-padding
        }
        keep[t] = r;                                   // reuse for SE-mean pass
    }

    {
        float s = s3, ss = ss3;
        #pragma unroll
        for (int m = 32; m > 0; m >>= 1) {
            s  += __shfl_xor(s,  m);
            ss += __shfl_xor(ss, m);
        }
        if (lane == 0) { ls[wid] = s; lss[wid] = ss; }
        __syncthreads();
        if (tid == 0) {
            float st = 0.f, sst = 0.f;
            #pragma unroll
            for (int i = 0; i < 8; ++i) { st += ls[i]; sst += lss[i]; }
            float m = st * (1.f/THW);
            float v = sst * (1.f/THW) - m*m;
            float is = 1.f / sqrtf(v + EPS);
            g_stats[SM3  + bc] = m;
            g_stats[SIS3 + bc] = is;
            sa = is; sb = -m * is;
        }
        __syncthreads();
    }

    // ---- phase D: SE mean of relu(norm3(h3)) from kept registers -------------
    const float a3 = sa, b3 = sb;
    float sse = 0.f;
    #pragma unroll
    for (int t = 0; t < T_; ++t) {
        uint_t uu[4] = {keep[t].x, keep[t].y, keep[t].z, keep[t].w};
        #pragma unroll
        for (int j = 0; j < 4; ++j) {
            sse += fmaxf(fmaf(__uint_as_float(uu[j] << 16),         a3, b3), 0.f);
            sse += fmaxf(fmaf(__uint_as_float(uu[j] & 0xffff0000u), a3, b3), 0.f);
        }
    }
    #pragma unroll
    for (int m = 32; m > 0; m >>= 1) sse += __shfl_xor(sse, m);
    if (lane == 0) ls[wid] = sse;
    __syncthreads();
    if (tid == 0) {
        float st = 0.f;
        #pragma unroll
        for (int i = 0; i < 8; ++i) st += ls[i];
        g_stats[SSES + bc] = st * (1.f/THW);
    }
}

// ------------ SE MLP -> fold sigmoid scale into proj's alpha/beta -------------
__global__ __launch_bounds__(256) void k_semlp(const float* __restrict__ wse1,
                                               const float* __restrict__ wse2) {
    __shared__ float mv[HID];
    __shared__ float y1[64];
    const int bb = blockIdx.x, tid = threadIdx.x;
    mv[tid] = g_stats[SSES + bb*HID + tid];
    __syncthreads();
    if (tid < 64) {
        float acc = 0.f;
        #pragma unroll 8
        for (int c = 0; c < HID; ++c) acc = fmaf(wse1[tid*HID + c], mv[c], acc);
        y1[tid] = fmaxf(acc, 0.f);
    }
    __syncthreads();
    float z = 0.f;
    #pragma unroll
    for (int c = 0; c < 64; ++c) z = fmaf(wse2[tid*64 + c], y1[c], z);
    float se = 1.f / (1.f + expf(-z));
    const int bc = bb*HID + tid;
    float al = g_stats[SIS3 + bc] * se;
    if (tid >= 32 && tid < 64) al = 0.f;   // zero-TIM channels: exact zero contribution
    g_stats[SAL + bc] = al;
    g_stats[SBE + bc] = -g_stats[SM3 + bc] * al;
}

// ============ proj 1x1 via MFMA (uint2 B-stage, alpha==0 skip) ================
__global__ __launch_bounds__(256) void k_proj(const ushort_t* __restrict__ h3,
                                              float* __restrict__ proj) {
    __shared__ ushort_t Bs[64*136];      // B[klocal][n], stride 136, rotated cols
    const int tid = threadIdx.x;
    const int bb  = blockIdx.y;
    const int pos0 = blockIdx.x * 128;
    const int lane = tid & 63, wv = tid >> 6;
    const int q = lane >> 4, ln = lane & 15;

    f32x4 acc[4][2];
    #pragma unroll
    for (int i = 0; i < 4; ++i) {
        acc[i][0] = (f32x4){0.f,0.f,0.f,0.f};
        acc[i][1] = (f32x4){0.f,0.f,0.f,0.f};
    }

    for (int kc = 0; kc < 4; ++kc) {
        #pragma unroll
        for (int i = 0; i < 8; ++i) {
            int lin = i*1024 + tid*4;
            int kl = lin >> 7, n0 = lin & 127;
            int ch = bb*HID + kc*64 + kl;
            float al = g_stats[SAL + ch], be = g_stats[SBE + ch];
            ushort_t* d = &Bs[kl*136 + ((n0 + 16*((kl>>3)&7)) & 127)];
            if (al == 0.f) {                 // zero-forced TIM channels
                d[0] = 0; d[1] = 0; d[2] = 0; d[3] = 0;
            } else {
                uint2 u = *(const uint2*)&h3[(size_t)ch * THW + pos0 + n0];
                float f0 = __uint_as_float(u.x << 16);
                float f1 = __uint_as_float(u.x & 0xffff0000u);
                float f2 = __uint_as_float(u.y << 16);
                float f3 = __uint_as_float(u.y & 0xffff0000u);
                d[0] = f2bf(fmaxf(fmaf(f0, al, be), 0.f));
                d[1] = f2bf(fmaxf(fmaf(f1, al, be), 0.f));
                d[2] = f2bf(fmaxf(fmaf(f2, al, be), 0.f));
                d[3] = f2bf(fmaxf(fmaf(f3, al, be), 0.f));
            }
        }
        __syncthreads();

        #pragma unroll
        for (int ks = 0; ks < 2; ++ks) {
            int kg = kc*2 + ks;
            bf16x8 af[4];
            #pragma unroll
            for (int ot = 0; ot < 4; ++ot)
                af[ot] = *(const bf16x8*)&g_wpack[16384 + ((kg*4+ot)<<9) + lane*8];
            bf16x8 bfr[2];
            #pragma unroll
            for (int nt = 0; nt < 2; ++nt) {
                union { short s[8]; bf16x8 v; } bu;
                #pragma unroll
                for (int j = 0; j < 8; ++j) {
                    int kl = ks*32 + q*8 + j;
                    int nn = (wv*32 + nt*16 + ln + 16*((kl>>3)&7)) & 127;
                    bu.s[j] = (short)Bs[kl*136 + nn];
                }
                bfr[nt] = bu.v;
            }
            #pragma unroll
            for (int ot = 0; ot < 4; ++ot)
                #pragma unroll
                for (int nt = 0; nt < 2; ++nt)
                    acc[ot][nt] = __builtin_amdgcn_mfma_f32_16x16x32_bf16(
                        af[ot], bfr[nt], acc[ot][nt], 0, 0, 0);
        }
        __syncthreads();
    }

    #pragma unroll
    for (int ot = 0; ot < 4; ++ot)
        #pragma unroll
        for (int nt = 0; nt < 2; ++nt)
            #pragma unroll
            for (int r = 0; r < 4; ++r) {
                int o = ot*16 + q*4 + r;
                int n = wv*32 + nt*16 + ln;
                proj[((size_t)bb*COUT + o)*THW + pos0 + n] = acc[ot][nt][r];
            }
}

// ------------ final fused: proj stats + norm + shortcut + maxpool -------------
__global__ __launch_bounds__(1024) void k_final(const float* __restrict__ proj,
                                                const float* __restrict__ x,
                                                float* __restrict__ out, int b0) {
    const int bo  = blockIdx.x;
    const int tid = threadIdx.x;
    const float* p = proj + (size_t)bo * THW;

    float s = 0.f, ss = 0.f;
    #pragma unroll
    for (int i = 0; i < THW/(1024*4); ++i) {
        float4 u = *(const float4*)(p + i*4096 + tid*4);
        s += u.x; ss = fmaf(u.x, u.x, ss);
        s += u.y; ss = fmaf(u.y, u.y, ss);
        s += u.z; ss = fmaf(u.z, u.z, ss);
        s += u.w; ss = fmaf(u.w, u.w, ss);
    }
    #pragma unroll
    for (int off = 32; off > 0; off >>= 1) {
        s  += __shfl_down(s,  off, 64);
        ss += __shfl_down(ss, off, 64);
    }
    __shared__ float ls[16], lss[16];
    __shared__ float sa, sb;
    int wid = tid >> 6, lane = tid & 63;
    if (lane == 0) { ls[wid] = s; lss[wid] = ss; }
    __syncthreads();
    if (tid == 0) {
        float st = 0.f, sst = 0.f;
        #pragma unroll
        for (int i = 0; i < 16; ++i) { st += ls[i]; sst += lss[i]; }
        float m = st * (1.f/THW);
        float v = sst * (1.f/THW) - m*m;
        float is = 1.f / sqrtf(v + EPS);
        sa = is; sb = -m * is;
    }
    __syncthreads();
    const float a = sa, bb = sb;

    const size_t gbase = (size_t)(b0*COUT + bo) * THW;
    float* op = out + (size_t)(b0*COUT + bo) * (T_*1024);
    #pragma unroll
    for (int i = 0; i < 16; ++i) {
        int idx = i*1024 + tid;
        int xx = idx & 31, yy = (idx >> 5) & 31, t = idx >> 10;
        float m = -3.4e38f;
        #pragma unroll
        for (int r = 0; r < 2; ++r) {
            size_t off = (size_t)t*HW_ + (size_t)(2*yy + r)*W_ + 2*xx;
            float2 p2 = *(const float2*)(p + off);
            float2 x2 = *(const float2*)(x + gbase + off);
            float v0 = fmaf(p2.x, a, bb) + x2.x;
            float v1 = fmaf(p2.y, a, bb) + x2.y;
            m = fmaxf(m, fmaxf(v0, v1));
        }
        op[idx] = m;
    }
}

extern "C" void kernel_launch(void* const* d_in, const int* in_sizes, int n_in,
                              void* d_out, int out_size, void* d_ws, size_t ws_size,
                              hipStream_t stream) {
    const float* x     = (const float*)d_in[0];
    const float* w1    = (const float*)d_in[1];
    const float* wdws  = (const float*)d_in[2];
    const float* wdwt  = (const float*)d_in[3];
    const float* wse1  = (const float*)d_in[4];
    const float* wse2  = (const float*)d_in[5];
    const float* wproj = (const float*)d_in[6];
    float* out = (float*)d_out;

    const size_t perb = 2ull * HID * THW * sizeof(ushort_t);   // 64 MB
    int nb = (ws_size >= 4*perb) ? 4 : (ws_size >= 2*perb) ? 2 : 1;

    k_prep<<<64, 256, 0, stream>>>(w1, wproj);

    for (int b0 = 0; b0 < B_; b0 += nb) {
        char* ws = (char*)d_ws;
        ushort_t* h1   = (ushort_t*)ws;
        ushort_t* h3   = h1;                                   // in-place per channel
        float*    proj = (float*)(ws + (size_t)nb * HID*THW*2);

        k_expand<<<dim3(THW/64, nb), 256, 0, stream>>>(x, h1, b0);
        k_mid   <<<nb*HID, 512, 0, stream>>>(h1, wdws, wdwt, h3);
        k_semlp <<<nb, 256, 0, stream>>>(wse1, wse2);
        k_proj  <<<dim3(THW/128, nb), 256, 0, stream>>>(h3, proj);
        k_final <<<nb*COUT, 1024, 0, stream>>>(proj, x, out, b0);
    }
}

// Round 5
// 367.536 us; speedup vs baseline: 1.0793x; 1.0793x over previous
//
#include <hip/hip_runtime.h>
#include <hip/hip_bf16.h>

#define B_   4
#define CIN  64
#define HID  256
#define COUT 64
#define T_   16
#define H_   64
#define W_   64
#define HW_  (H_*W_)       // 4096
#define THW  (T_*HW_)      // 65536
#define EPS  1e-5f

typedef unsigned short ushort_t;
typedef unsigned int   uint_t;
typedef short bf16x8 __attribute__((ext_vector_type(8)));
typedef float f32x4  __attribute__((ext_vector_type(4)));

// ---- stats in static device memory -------------------------------------------
#define SM3   4096
#define SIS3  5120
#define SSES  6144
#define SAL   7168
#define SBE   8192
__device__ float g_stats[10240];
// per-(bb, pos-block, channel) partial sums from k_expand epilogue (stats1)
__device__ float g_eps [4*1024*256];
__device__ float g_epss[4*1024*256];
// packed bf16 weights in MFMA fragment order: [0:16384) expand, [16384:32768) proj
__device__ ushort_t g_wpack[32768];

__device__ __forceinline__ float bf2f(ushort_t u) {
    return __uint_as_float(((uint_t)u) << 16);
}
__device__ __forceinline__ ushort_t f2bf(float f) {
    uint_t u = __float_as_uint(f);
    uint_t r = u + 0x7fffu + ((u >> 16) & 1u);   // round-to-nearest-even
    return (ushort_t)(r >> 16);
}
__device__ __forceinline__ void loadnorm8(const ushort_t* p, float a, float bb,
                                          float* v) {
    uint4 u = *(const uint4*)p;
    uint_t uu[4] = {u.x, u.y, u.z, u.w};
    #pragma unroll
    for (int j = 0; j < 4; ++j) {
        v[2*j]   = fmaxf(fmaf(__uint_as_float(uu[j] << 16),         a, bb), 0.f);
        v[2*j+1] = fmaxf(fmaf(__uint_as_float(uu[j] & 0xffff0000u), a, bb), 0.f);
    }
}
__device__ __forceinline__ void loadnorm4(const ushort_t* p, float a, float bb,
                                          float* v) {
    uint2 u = *(const uint2*)p;
    uint_t uu[2] = {u.x, u.y};
    #pragma unroll
    for (int j = 0; j < 2; ++j) {
        v[2*j]   = fmaxf(fmaf(__uint_as_float(uu[j] << 16),         a, bb), 0.f);
        v[2*j+1] = fmaxf(fmaf(__uint_as_float(uu[j] & 0xffff0000u), a, bb), 0.f);
    }
}
__device__ __forceinline__ void unpacknorm2(uint2 k, float a, float bb, float* v) {
    uint_t uu[2] = {k.x, k.y};
    #pragma unroll
    for (int j = 0; j < 2; ++j) {
        v[2*j]   = fmaxf(fmaf(__uint_as_float(uu[j] << 16),         a, bb), 0.f);
        v[2*j+1] = fmaxf(fmaf(__uint_as_float(uu[j] & 0xffff0000u), a, bb), 0.f);
    }
}

// ---- pack w1 + wproj into bf16 fragment order --------------------------------
__global__ __launch_bounds__(256) void k_prep(const float* __restrict__ w1,
                                              const float* __restrict__ wproj) {
    int idx = blockIdx.x*256 + threadIdx.x;        // 0..16383
    {
        int j = idx & 7, lane = (idx>>3) & 63, ot = (idx>>9) & 3;
        int ks = (idx>>11) & 1, wv = idx >> 12;
        int ln = lane & 15, q = lane >> 4;
        int o = wv*64 + ot*16 + ln, k = ks*32 + q*8 + j;
        g_wpack[idx] = f2bf(w1[o*CIN + k]);
    }
    {
        int j = idx & 7, lane = (idx>>3) & 63, ot = (idx>>9) & 3, kg = idx >> 11;
        int ln = lane & 15, q = lane >> 4;
        int o = ot*16 + ln, k = kg*32 + q*8 + j;
        g_wpack[16384 + idx] = f2bf(wproj[o*HID + k]);
    }
}

// ============ expand 1x1 via MFMA + fused per-channel stats1 partials =========
__global__ __launch_bounds__(256) void k_expand(const float* __restrict__ x,
                                                ushort_t* __restrict__ h1, int b0) {
    union SMem {
        ushort_t Bs[64*72];          // B[k][n], stride 72, rotated cols (18.4 KB)
        float    red[2][256][16];    // per-channel per-16lane partials (32 KB)
    };
    __shared__ SMem sm;
    const int tid = threadIdx.x;
    const int bb  = blockIdx.y, gb = b0 + bb;
    const int pos0 = blockIdx.x * 64;
    const int lane = tid & 63, wv = tid >> 6;
    const int q = lane >> 4, ln = lane & 15;

    bf16x8 af[2][4];
    #pragma unroll
    for (int ks = 0; ks < 2; ++ks)
        #pragma unroll
        for (int ot = 0; ot < 4; ++ot)
            af[ks][ot] = *(const bf16x8*)&g_wpack[(((wv*2+ks)*4+ot)<<9) + lane*8];

    #pragma unroll
    for (int i = 0; i < 4; ++i) {
        int lin = i*1024 + tid*4;
        int k = lin >> 6, n0 = lin & 63;
        float4 v = *(const float4*)&x[(size_t)(gb*CIN + k) * THW + pos0 + n0];
        ushort_t* d = &sm.Bs[k*72 + ((n0 + 16*((k>>3)&3)) & 63)];
        d[0] = f2bf(v.x); d[1] = f2bf(v.y); d[2] = f2bf(v.z); d[3] = f2bf(v.w);
    }
    __syncthreads();

    f32x4 acc[4][4];
    #pragma unroll
    for (int i = 0; i < 4; ++i)
        #pragma unroll
        for (int j = 0; j < 4; ++j)
            acc[i][j] = (f32x4){0.f,0.f,0.f,0.f};

    #pragma unroll
    for (int ks = 0; ks < 2; ++ks) {
        bf16x8 bfr[4];
        #pragma unroll
        for (int nt = 0; nt < 4; ++nt) {
            union { short s[8]; bf16x8 v; } bu;
            #pragma unroll
            for (int j = 0; j < 8; ++j) {
                int k = ks*32 + q*8 + j;
                int nn = (nt*16 + ln + 16*((k>>3)&3)) & 63;
                bu.s[j] = (short)sm.Bs[k*72 + nn];
            }
            bfr[nt] = bu.v;
        }
        #pragma unroll
        for (int ot = 0; ot < 4; ++ot)
            #pragma unroll
            for (int nt = 0; nt < 4; ++nt)
                acc[ot][nt] = __builtin_amdgcn_mfma_f32_16x16x32_bf16(
                    af[ks][ot], bfr[nt], acc[ot][nt], 0, 0, 0);
    }

    // epilogue: store + accumulate per-lane per-channel partial sums
    float sp_[16], ssp_[16];
    #pragma unroll
    for (int i = 0; i < 16; ++i) { sp_[i] = 0.f; ssp_[i] = 0.f; }

    #pragma unroll
    for (int ot = 0; ot < 4; ++ot)
        #pragma unroll
        for (int nt = 0; nt < 4; ++nt)
            #pragma unroll
            for (int r = 0; r < 4; ++r) {
                float vv = acc[ot][nt][r];
                int o = wv*64 + ot*16 + q*4 + r;
                int n = nt*16 + ln;
                h1[((size_t)bb*HID + o)*THW + pos0 + n] = f2bf(vv);
                sp_[ot*4+r] += vv;
                ssp_[ot*4+r] = fmaf(vv, vv, ssp_[ot*4+r]);
            }

    __syncthreads();           // all waves done reading Bs before union reuse
    #pragma unroll
    for (int i = 0; i < 16; ++i) {
        int o = wv*64 + (i>>2)*16 + q*4 + (i&3);
        sm.red[0][o][ln] = sp_[i];
        sm.red[1][o][ln] = ssp_[i];
    }
    __syncthreads();
    {
        float s = 0.f, ss = 0.f;
        #pragma unroll
        for (int l = 0; l < 16; ++l) {
            s  += sm.red[0][tid][l];
            ss += sm.red[1][tid][l];
        }
        size_t base = ((size_t)bb*1024 + blockIdx.x)*256 + tid;
        g_eps [base] = s;
        g_epss[base] = ss;
    }
}

// ===== fused stage2+stage3: spatial dw3x3 -> IN -> relu -> temporal dw3 =======
// one block (1024 thr) per (bb, channel); dws output in keep[16] uint2 registers
// (4 elems/thread; phase A fully unrolled -> keep[] statically indexed, no spill)
__global__ __launch_bounds__(1024) void k_mid(const ushort_t* __restrict__ h1,
                                              const float* __restrict__ wdws,
                                              const float* __restrict__ wdwt,
                                              ushort_t* __restrict__ h3) {
    const int tid = threadIdx.x;                  // 0..1023
    const int bc  = blockIdx.x;
    const int o   = bc & (HID-1);
    const int bb  = bc >> 8;
    const int wid = tid >> 6, lane = tid & 63;

    if (o >= 32 && o < 64) {                      // zero-forced TIM channels
        if (tid == 0) {
            g_stats[SM3  + bc] = 0.f;
            g_stats[SIS3 + bc] = 1.f / sqrtf(EPS);
            g_stats[SSES + bc] = 0.f;
        }
        return;
    }

    __shared__ float pl[2][64*65];                // double-buffered norm'd plane
    __shared__ float ls[16], lss[16];
    __shared__ float sa, sb;

    // ---- stats1 for this channel from k_expand partials (L3-hot) ------------
    {
        const float* ps  = &g_eps [((size_t)bb*1024)*256 + o];
        const float* pss = &g_epss[((size_t)bb*1024)*256 + o];
        float s  = ps [(size_t)tid*256];
        float ss = pss[(size_t)tid*256];
        #pragma unroll
        for (int m = 32; m > 0; m >>= 1) {
            s  += __shfl_xor(s,  m);
            ss += __shfl_xor(ss, m);
        }
        if (lane == 0) { ls[wid] = s; lss[wid] = ss; }
        __syncthreads();
        if (tid == 0) {
            float st = 0.f, sst = 0.f;
            #pragma unroll
            for (int i = 0; i < 16; ++i) { st += ls[i]; sst += lss[i]; }
            float m = st * (1.f/THW);
            float v = sst * (1.f/THW) - m*m;
            float is = 1.f / sqrtf(v + EPS);
            sa = is; sb = -m * is;
        }
        __syncthreads();
    }
    const float a1 = sa, b1 = sb;

    const int fut = (o < 32) ? 1 : 0;             // TIM future-shifted channel
    const int y   = tid >> 4;                     // 0..63
    const int x0  = (tid & 15) * 4;               // 0..60
    const ushort_t* chp = h1 + (size_t)bc * THW;

    float wf[9];
    #pragma unroll
    for (int k = 0; k < 9; ++k) wf[k] = wdws[o*9 + k];

    // prologue: stage normalized input plane for output t=0
    {
        const ushort_t* sp = chp + (size_t)(fut ? 1 : 0) * HW_ + tid*4;
        float v[4];
        loadnorm4(sp, a1, b1, v);
        float* dst = &pl[0][y*65 + x0];
        #pragma unroll
        for (int i = 0; i < 4; ++i) dst[i] = v[i];
    }
    __syncthreads();

    // ---- phase A: spatial 3x3 conv, outputs kept in registers ----------------
    uint2 keep[16];
    float s2 = 0.f, ss2 = 0.f;
    const int lastp = fut ? (T_-2) : (T_-1);      // last output with real input

    #pragma unroll
    for (int t = 0; t < T_; ++t) {
        if (t < lastp) {                          // stage next plane, other buf
            int np = t + 1;
            const ushort_t* sp = chp + (size_t)(fut ? np+1 : np)*HW_ + tid*4;
            float v[4];
            loadnorm4(sp, a1, b1, v);
            float* dst = &pl[np & 1][y*65 + x0];
            #pragma unroll
            for (int i = 0; i < 4; ++i) dst[i] = v[i];
        }
        if (fut && t == T_-1) {
            keep[t] = (uint2){0u, 0u};            // TIM zero plane: dws out = 0
        } else {
            const float* plane = pl[t & 1];
            float v[3][6];
            #pragma unroll
            for (int dy = 0; dy < 3; ++dy) {
                int yy = y + dy - 1;
                if (yy < 0 || yy >= H_) {
                    #pragma unroll
                    for (int j = 0; j < 6; ++j) v[dy][j] = 0.f;
                } else {
                    const float* rp = &plane[yy*65];
                    v[dy][0] = (x0 == 0)  ? 0.f : rp[x0-1];
                    #pragma unroll
                    for (int i = 0; i < 4; ++i) v[dy][1+i] = rp[x0+i];
                    v[dy][5] = (x0 == 60) ? 0.f : rp[x0+4];
                }
            }
            uint_t outp[2];
            #pragma unroll
            for (int i2 = 0; i2 < 2; ++i2) {
                float o0 = 0.f, o1 = 0.f;
                #pragma unroll
                for (int dy = 0; dy < 3; ++dy)
                    #pragma unroll
                    for (int dx = 0; dx < 3; ++dx) {
                        float w = wf[dy*3+dx];
                        o0 = fmaf(w, v[dy][2*i2 + dx],     o0);
                        o1 = fmaf(w, v[dy][2*i2 + 1 + dx], o1);
                    }
                ushort_t u0 = f2bf(o0), u1 = f2bf(o1);
                float r0 = bf2f(u0), r1 = bf2f(u1);
                s2 += r0 + r1; ss2 = fmaf(r0, r0, fmaf(r1, r1, ss2));
                outp[i2] = (uint_t)u0 | ((uint_t)u1 << 16);
            }
            keep[t].x = outp[0]; keep[t].y = outp[1];
        }
        __syncthreads();
    }

    // ---- phase B: stats2 block-reduce (never touches HBM) --------------------
    {
        float s = s2, ss = ss2;
        #pragma unroll
        for (int m = 32; m > 0; m >>= 1) {
            s  += __shfl_xor(s,  m);
            ss += __shfl_xor(ss, m);
        }
        if (lane == 0) { ls[wid] = s; lss[wid] = ss; }
        __syncthreads();
        if (tid == 0) {
            float st = 0.f, sst = 0.f;
            #pragma unroll
            for (int i = 0; i < 16; ++i) { st += ls[i]; sst += lss[i]; }
            float m = st * (1.f/THW);
            float v = sst * (1.f/THW) - m*m;
            float is = 1.f / sqrtf(v + EPS);
            sa = is; sb = -m * is;
        }
        __syncthreads();
    }
    const float a2 = sa, b2 = sb;
    // note: for fut channels keep[15]==0 -> unpacknorm2 gives relu(b2) == znorm

    // ---- phase C: temporal dw3 from registers, write h3, stats3 --------------
    const float w0 = wdwt[o*3+0], w1 = wdwt[o*3+1], w2 = wdwt[o*3+2];
    ushort_t* op = h3 + (size_t)bc * THW + tid*4;

    float p[4], c[4], n[4];
    #pragma unroll
    for (int i = 0; i < 4; ++i) p[i] = 0.f;
    unpacknorm2(keep[0], a2, b2, c);
    unpacknorm2(keep[1], a2, b2, n);

    float s3 = 0.f, ss3 = 0.f;
    #pragma unroll
    for (int t = 0; t < T_; ++t) {
        uint_t outp[2];
        #pragma unroll
        for (int i2 = 0; i2 < 2; ++i2) {
            float o0 = fmaf(w0, p[2*i2],   fmaf(w1, c[2*i2],   w2 * n[2*i2]));
            float o1 = fmaf(w0, p[2*i2+1], fmaf(w1, c[2*i2+1], w2 * n[2*i2+1]));
            ushort_t u0 = f2bf(o0), u1 = f2bf(o1);
            float r0 = bf2f(u0), r1 = bf2f(u1);
            s3 += r0 + r1; ss3 = fmaf(r0, r0, fmaf(r1, r1, ss3));
            outp[i2] = (uint_t)u0 | ((uint_t)u1 << 16);
        }
        uint2 r; r.x = outp[0]; r.y = outp[1];
        *(uint2*)(op + (size_t)t*HW_) = r;

        #pragma unroll
        for (int i = 0; i < 4; ++i) { p[i] = c[i]; c[i] = n[i]; }
        if (t + 2 < T_) unpacknorm2(keep[t+2], a2, b2, n);
        else {
            #pragma unroll
            for (int i = 0; i < 4; ++i) n[i] = 0.f;   // true conv zero-padding
        }
        keep[t] = r;                                   // reuse for SE-mean pass
    }

    {
        float s = s3, ss = ss3;
        #pragma unroll
        for (int m = 32; m > 0; m >>= 1) {
            s  += __shfl_xor(s,  m);
            ss += __shfl_xor(ss, m);
        }
        if (lane == 0) { ls[wid] = s; lss[wid] = ss; }
        __syncthreads();
        if (tid == 0) {
            float st = 0.f, sst = 0.f;
            #pragma unroll
            for (int i = 0; i < 16; ++i) { st += ls[i]; sst += lss[i]; }
            float m = st * (1.f/THW);
            float v = sst * (1.f/THW) - m*m;
            float is = 1.f / sqrtf(v + EPS);
            g_stats[SM3  + bc] = m;
            g_stats[SIS3 + bc] = is;
            sa = is; sb = -m * is;
        }
        __syncthreads();
    }

    // ---- phase D: SE mean of relu(norm3(h3)) from kept registers -------------
    const float a3 = sa, b3 = sb;
    float sse = 0.f;
    #pragma unroll
    for (int t = 0; t < T_; ++t) {
        uint_t uu[2] = {keep[t].x, keep[t].y};
        #pragma unroll
        for (int j = 0; j < 2; ++j) {
            sse += fmaxf(fmaf(__uint_as_float(uu[j] << 16),         a3, b3), 0.f);
            sse += fmaxf(fmaf(__uint_as_float(uu[j] & 0xffff0000u), a3, b3), 0.f);
        }
    }
    #pragma unroll
    for (int m = 32; m > 0; m >>= 1) sse += __shfl_xor(sse, m);
    if (lane == 0) ls[wid] = sse;
    __syncthreads();
    if (tid == 0) {
        float st = 0.f;
        #pragma unroll
        for (int i = 0; i < 16; ++i) st += ls[i];
        g_stats[SSES + bc] = st * (1.f/THW);
    }
}

// ------------ SE MLP -> fold sigmoid scale into proj's alpha/beta -------------
__global__ __launch_bounds__(256) void k_semlp(const float* __restrict__ wse1,
                                               const float* __restrict__ wse2) {
    __shared__ float mv[HID];
    __shared__ float y1[64];
    const int bb = blockIdx.x, tid = threadIdx.x;
    mv[tid] = g_stats[SSES + bb*HID + tid];
    __syncthreads();
    if (tid < 64) {
        float acc = 0.f;
        #pragma unroll 8
        for (int c = 0; c < HID; ++c) acc = fmaf(wse1[tid*HID + c], mv[c], acc);
        y1[tid] = fmaxf(acc, 0.f);
    }
    __syncthreads();
    float z = 0.f;
    #pragma unroll
    for (int c = 0; c < 64; ++c) z = fmaf(wse2[tid*64 + c], y1[c], z);
    float se = 1.f / (1.f + expf(-z));
    const int bc = bb*HID + tid;
    float al = g_stats[SIS3 + bc] * se;
    if (tid >= 32 && tid < 64) al = 0.f;   // zero-TIM channels: exact zero contribution
    g_stats[SAL + bc] = al;
    g_stats[SBE + bc] = -g_stats[SM3 + bc] * al;
}

// ============ proj 1x1 via MFMA (uint2 B-stage, alpha==0 skip) ================
__global__ __launch_bounds__(256) void k_proj(const ushort_t* __restrict__ h3,
                                              float* __restrict__ proj) {
    __shared__ ushort_t Bs[64*136];      // B[klocal][n], stride 136, rotated cols
    const int tid = threadIdx.x;
    const int bb  = blockIdx.y;
    const int pos0 = blockIdx.x * 128;
    const int lane = tid & 63, wv = tid >> 6;
    const int q = lane >> 4, ln = lane & 15;

    f32x4 acc[4][2];
    #pragma unroll
    for (int i = 0; i < 4; ++i) {
        acc[i][0] = (f32x4){0.f,0.f,0.f,0.f};
        acc[i][1] = (f32x4){0.f,0.f,0.f,0.f};
    }

    for (int kc = 0; kc < 4; ++kc) {
        #pragma unroll
        for (int i = 0; i < 8; ++i) {
            int lin = i*1024 + tid*4;
            int kl = lin >> 7, n0 = lin & 127;
            int ch = bb*HID + kc*64 + kl;
            float al = g_stats[SAL + ch], be = g_stats[SBE + ch];
            ushort_t* d = &Bs[kl*136 + ((n0 + 16*((kl>>3)&7)) & 127)];
            if (al == 0.f) {                 // zero-forced TIM channels
                d[0] = 0; d[1] = 0; d[2] = 0; d[3] = 0;
            } else {
                uint2 u = *(const uint2*)&h3[(size_t)ch * THW + pos0 + n0];
                float f0 = __uint_as_float(u.x << 16);
                float f1 = __uint_as_float(u.x & 0xffff0000u);
                float f2 = __uint_as_float(u.y << 16);
                float f3 = __uint_as_float(u.y & 0xffff0000u);
                d[0] = f2bf(fmaxf(fmaf(f0, al, be), 0.f));
                d[1] = f2bf(fmaxf(fmaf(f1, al, be), 0.f));
                d[2] = f2bf(fmaxf(fmaf(f2, al, be), 0.f));
                d[3] = f2bf(fmaxf(fmaf(f3, al, be), 0.f));
            }
        }
        __syncthreads();

        #pragma unroll
        for (int ks = 0; ks < 2; ++ks) {
            int kg = kc*2 + ks;
            bf16x8 af[4];
            #pragma unroll
            for (int ot = 0; ot < 4; ++ot)
                af[ot] = *(const bf16x8*)&g_wpack[16384 + ((kg*4+ot)<<9) + lane*8];
            bf16x8 bfr[2];
            #pragma unroll
            for (int nt = 0; nt < 2; ++nt) {
                union { short s[8]; bf16x8 v; } bu;
                #pragma unroll
                for (int j = 0; j < 8; ++j) {
                    int kl = ks*32 + q*8 + j;
                    int nn = (wv*32 + nt*16 + ln + 16*((kl>>3)&7)) & 127;
                    bu.s[j] = (short)Bs[kl*136 + nn];
                }
                bfr[nt] = bu.v;
            }
            #pragma unroll
            for (int ot = 0; ot < 4; ++ot)
                #pragma unroll
                for (int nt = 0; nt < 2; ++nt)
                    acc[ot][nt] = __builtin_amdgcn_mfma_f32_16x16x32_bf16(
                        af[ot], bfr[nt], acc[ot][nt], 0, 0, 0);
        }
        __syncthreads();
    }

    #pragma unroll
    for (int ot = 0; ot < 4; ++ot)
        #pragma unroll
        for (int nt = 0; nt < 2; ++nt)
            #pragma unroll
            for (int r = 0; r < 4; ++r) {
                int o = ot*16 + q*4 + r;
                int n = wv*32 + nt*16 + ln;
                proj[((size_t)bb*COUT + o)*THW + pos0 + n] = acc[ot][nt][r];
            }
}

// ------------ final fused: proj stats + norm + shortcut + maxpool -------------
__global__ __launch_bounds__(1024) void k_final(const float* __restrict__ proj,
                                                const float* __restrict__ x,
                                                float* __restrict__ out, int b0) {
    const int bo  = blockIdx.x;
    const int tid = threadIdx.x;
    const float* p = proj + (size_t)bo * THW;

    float s = 0.f, ss = 0.f;
    #pragma unroll
    for (int i = 0; i < THW/(1024*4); ++i) {
        float4 u = *(const float4*)(p + i*4096 + tid*4);
        s += u.x; ss = fmaf(u.x, u.x, ss);
        s += u.y; ss = fmaf(u.y, u.y, ss);
        s += u.z; ss = fmaf(u.z, u.z, ss);
        s += u.w; ss = fmaf(u.w, u.w, ss);
    }
    #pragma unroll
    for (int off = 32; off > 0; off >>= 1) {
        s  += __shfl_down(s,  off, 64);
        ss += __shfl_down(ss, off, 64);
    }
    __shared__ float ls[16], lss[16];
    __shared__ float sa, sb;
    int wid = tid >> 6, lane = tid & 63;
    if (lane == 0) { ls[wid] = s; lss[wid] = ss; }
    __syncthreads();
    if (tid == 0) {
        float st = 0.f, sst = 0.f;
        #pragma unroll
        for (int i = 0; i < 16; ++i) { st += ls[i]; sst += lss[i]; }
        float m = st * (1.f/THW);
        float v = sst * (1.f/THW) - m*m;
        float is = 1.f / sqrtf(v + EPS);
        sa = is; sb = -m * is;
    }
    __syncthreads();
    const float a = sa, bb = sb;

    const size_t gbase = (size_t)(b0*COUT + bo) * THW;
    float* op = out + (size_t)(b0*COUT + bo) * (T_*1024);
    #pragma unroll
    for (int i = 0; i < 16; ++i) {
        int idx = i*1024 + tid;
        int xx = idx & 31, yy = (idx >> 5) & 31, t = idx >> 10;
        float m = -3.4e38f;
        #pragma unroll
        for (int r = 0; r < 2; ++r) {
            size_t off = (size_t)t*HW_ + (size_t)(2*yy + r)*W_ + 2*xx;
            float2 p2 = *(const float2*)(p + off);
            float2 x2 = *(const float2*)(x + gbase + off);
            float v0 = fmaf(p2.x, a, bb) + x2.x;
            float v1 = fmaf(p2.y, a, bb) + x2.y;
            m = fmaxf(m, fmaxf(v0, v1));
        }
        op[idx] = m;
    }
}

extern "C" void kernel_launch(void* const* d_in, const int* in_sizes, int n_in,
                              void* d_out, int out_size, void* d_ws, size_t ws_size,
                              hipStream_t stream) {
    const float* x     = (const float*)d_in[0];
    const float* w1    = (const float*)d_in[1];
    const float* wdws  = (const float*)d_in[2];
    const float* wdwt  = (const float*)d_in[3];
    const float* wse1  = (const float*)d_in[4];
    const float* wse2  = (const float*)d_in[5];
    const float* wproj = (const float*)d_in[6];
    float* out = (float*)d_out;

    const size_t perb = 2ull * HID * THW * sizeof(ushort_t);   // 64 MB
    int nb = (ws_size >= 4*perb) ? 4 : (ws_size >= 2*perb) ? 2 : 1;

    k_prep<<<64, 256, 0, stream>>>(w1, wproj);

    for (int b0 = 0; b0 < B_; b0 += nb) {
        char* ws = (char*)d_ws;
        ushort_t* h1   = (ushort_t*)ws;
        ushort_t* h3   = h1;                                   // in-place per channel
        float*    proj = (float*)(ws + (size_t)nb * HID*THW*2);

        k_expand<<<dim3(THW/64, nb), 256, 0, stream>>>(x, h1, b0);
        k_mid   <<<nb*HID, 1024, 0, stream>>>(h1, wdws, wdwt, h3);
        k_semlp <<<nb, 256, 0, stream>>>(wse1, wse2);
        k_proj  <<<dim3(THW/128, nb), 256, 0, stream>>>(h3, proj);
        k_final <<<nb*COUT, 1024, 0, stream>>>(proj, x, out, b0);
    }
}